// Round 4
// baseline (205.160 us; speedup 1.0000x reference)
//
#include <hip/hip_runtime.h>
#include <hip/hip_bf16.h>
#include <math.h>

#define NPTS 100000
#define NPAD 100352      // 784*128 (784 row tiles: divisible by 8 XCDs)
#define PDIM 256
#define KCOMP 64

typedef float v4f __attribute__((ext_vector_type(4)));
typedef __bf16 v8bf __attribute__((ext_vector_type(8)));

// ---------- async global->LDS (16B per lane; LDS base wave-uniform) ----------
__device__ __forceinline__ void gload_lds16(const void* g, void* lds) {
    __builtin_amdgcn_global_load_lds(
        (const __attribute__((address_space(1))) void*)(uintptr_t)g,
        (__attribute__((address_space(3))) void*)(uint32_t)(uintptr_t)lds,
        16, 0, 0);
}

// ---------- kernel 1: per-component prep ----------
// D = I + M^T M ; parallel Cholesky D = L L^T ; Bt[k*16+r][p] = (L^{-1} M^T)[r][p]
// stored PRE-SWIZZLED: element index p ^= ((crow&7)<<3). cvec[k] = logSA - sum log L_jj + logpi[k].
__global__ __launch_bounds__(256) void prep_comp(const float* __restrict__ M,
                                                 const float* __restrict__ pi,
                                                 __bf16* __restrict__ Bt,
                                                 float* __restrict__ cvec,
                                                 float logSA) {
    __shared__ float Ml[256][16];
    __shared__ float S[16][17];
    __shared__ float sh_logpi;
    const int k = blockIdx.x, t = threadIdx.x;

    const float4* src = (const float4*)(M + (size_t)k * 4096 + (size_t)t * 16);
    float4 a0 = src[0], a1 = src[1], a2 = src[2], a3 = src[3];
    ((float4*)Ml[t])[0] = a0; ((float4*)Ml[t])[1] = a1;
    ((float4*)Ml[t])[2] = a2; ((float4*)Ml[t])[3] = a3;

    if (t < 64) {
        float v = pi[t];
        float mx = v;
        for (int off = 32; off; off >>= 1) mx = fmaxf(mx, __shfl_xor(mx, off));
        float e = __expf(v - mx);
        float s = e;
        for (int off = 32; off; off >>= 1) s += __shfl_xor(s, off);
        if (t == 0) sh_logpi = pi[k] - mx - logf(s);
    }
    __syncthreads();

    {
        int r = t >> 4, c = t & 15;
        float s = (r == c) ? 1.0f : 0.0f;
        for (int p = 0; p < 256; ++p) s += Ml[p][r] * Ml[p][c];
        S[r][c] = s;
    }
    __syncthreads();

    for (int j = 0; j < 16; ++j) {
        if (t == 0) S[j][j] = sqrtf(S[j][j]);
        __syncthreads();
        if (t > j && t < 16) S[t][j] = S[t][j] / S[j][j];
        __syncthreads();
        {
            int r = t >> 4, c = t & 15;
            if (r > j && c > j && c <= r) S[r][c] -= S[r][j] * S[c][j];
        }
        __syncthreads();
    }

    if (t == 0) {
        float ldet = 0.0f;
        for (int j = 0; j < 16; ++j) ldet += logf(S[j][j]);
        cvec[k] = logSA - ldet + sh_logpi;
    }

    float m[16] = {a0.x, a0.y, a0.z, a0.w, a1.x, a1.y, a1.z, a1.w,
                   a2.x, a2.y, a2.z, a2.w, a3.x, a3.y, a3.z, a3.w};
    float y[16];
#pragma unroll
    for (int r = 0; r < 16; ++r) {
        float v = m[r];
#pragma unroll
        for (int q = 0; q < r; ++q) v -= S[r][q] * y[q];
        y[r] = v / S[r][r];
    }
#pragma unroll
    for (int r = 0; r < 16; ++r) {
        const int crow = k * 16 + r;
        Bt[(size_t)crow * 256 + (t ^ ((crow & 7) << 3))] = (__bf16)y[r];
    }
}

// ---------- kernel 2: X fp32 -> bf16, PRE-SWIZZLED (elem ^= (row&7)<<3), pad rows zero ----------
__global__ __launch_bounds__(256) void convert_X(const float* __restrict__ X,
                                                 __bf16* __restrict__ Xb) {
    size_t i = ((size_t)blockIdx.x * 256 + threadIdx.x) * 8;
    int n = (int)(i >> 8);
    int kk = (int)(i & 255);
    v8bf o;
    if (n < NPTS) {
        const float4* s4 = (const float4*)(X + i);
        float4 a = s4[0], b = s4[1];
        o[0] = (__bf16)a.x; o[1] = (__bf16)a.y; o[2] = (__bf16)a.z; o[3] = (__bf16)a.w;
        o[4] = (__bf16)b.x; o[5] = (__bf16)b.y; o[6] = (__bf16)b.z; o[7] = (__bf16)b.w;
    } else {
        for (int j = 0; j < 8; ++j) o[j] = (__bf16)0.0f;
    }
    *(v8bf*)(Xb + (size_t)n * 256 + (kk ^ ((n & 7) << 3))) = o;
}

// ---------- kernel 3: GEMM + fused quad/density epilogue ----------
// Full-K single-stage: 128x128 tile, A+B tiles (K=256 entire) staged in one shot
// into 128 KB LDS; ONE vmcnt(0)+barrier; 64 MFMA/wave with zero inner barriers.
// 512 threads = 8 waves = 2 waves/SIMD. Swizzled reads (conflict-free), XCD swizzle.
__global__ __launch_bounds__(512) void gemm_density(const __bf16* __restrict__ Xb,
                                                    const __bf16* __restrict__ Bt,
                                                    const float* __restrict__ cvec,
                                                    float* __restrict__ dens) {
    __shared__ __bf16 As[128 * 256];   // 64 KB
    __shared__ __bf16 Bs[128 * 256];   // 64 KB
    const int bid = blockIdx.x;
    const int xcd = bid & 7, j = bid >> 3;
    const int rt = xcd + ((j >> 3) << 3);   // 0..783
    const int ct = j & 7;
    const int row0 = rt << 7, col0 = ct << 7;
    const int tid = threadIdx.x;
    const int w = tid >> 6, lane = tid & 63;
    const int wm = w >> 1, wn = w & 1;      // 4 x 2 wave grid: 32 rows x 64 cols each
    const int lo = lane & 15, hi = lane >> 4;
    const int sw = lo & 7;

    // ---- single-shot staging: 8 A-loads + 8 B-loads per thread, all in flight ----
#pragma unroll
    for (int i = 0; i < 8; ++i) {
        const int base16 = (i << 9) + (w << 6);        // wave-uniform 16B-granule index
        const int flat = base16 + lane;
        const int r_ = flat >> 5;                      // 0..127
        const int g_ = flat & 31;                      // 16B granule within row
        gload_lds16(Xb + (size_t)(row0 + r_) * 256 + (g_ << 3), As + ((size_t)base16 << 3));
        gload_lds16(Bt + (size_t)(col0 + r_) * 256 + (g_ << 3), Bs + ((size_t)base16 << 3));
    }
    asm volatile("s_waitcnt vmcnt(0)" ::: "memory");
    __syncthreads();

    // ---- straight-line compute: 8 k-subtiles x (2x4) MFMA, no barriers ----
    v4f acc[2][4] = {};
#pragma unroll
    for (int kt = 0; kt < 8; ++kt) {
        const int gph = (((kt << 2) + hi) ^ sw) << 3;  // swizzled k-granule byte/elem offset
        v8bf af[2], bg[4];
#pragma unroll
        for (int m = 0; m < 2; ++m)
            af[m] = *(const v8bf*)&As[(wm * 32 + m * 16 + lo) * 256 + gph];
#pragma unroll
        for (int n = 0; n < 4; ++n)
            bg[n] = *(const v8bf*)&Bs[(wn * 64 + n * 16 + lo) * 256 + gph];
#pragma unroll
        for (int m = 0; m < 2; ++m)
#pragma unroll
            for (int n = 0; n < 4; ++n)
                acc[m][n] = __builtin_amdgcn_mfma_f32_16x16x32_bf16(af[m], bg[n], acc[m][n], 0, 0, 0);
    }

    // ---- epilogue: quad per (row, 16-col group) then density ----
#pragma unroll
    for (int m = 0; m < 2; ++m) {
        const int rowb = row0 + wm * 32 + m * 16 + hi * 4;
#pragma unroll
        for (int n = 0; n < 4; ++n) {
            const int kc = (col0 >> 4) + (wn << 2) + n;
            v4f q = acc[m][n] * acc[m][n];
#pragma unroll
            for (int off = 1; off < 16; off <<= 1) {
                v4f t;
                t[0] = __shfl_xor(q[0], off);
                t[1] = __shfl_xor(q[1], off);
                t[2] = __shfl_xor(q[2], off);
                t[3] = __shfl_xor(q[3], off);
                q += t;
            }
            if (lo < 4) {
                const float quad = q[lo];
                const float d = cvec[kc] - 128.0f * __logf(1.0f - quad);
                dens[(size_t)kc * NPAD + rowb + lo] = d;
            }
        }
    }
}

// ---------- kernel 4: logsumexp over k, global sum (branchless online) ----------
__global__ __launch_bounds__(256) void reduce_ll(const float* __restrict__ dens,
                                                 float* __restrict__ out) {
    const int n = blockIdx.x * 256 + threadIdx.x;
    float local = 0.0f;
    if (n < NPTS) {
        float m = dens[n];
        float s = 1.0f;
        for (int k = 1; k < 64; ++k) {
            float d = dens[(size_t)k * NPAD + n];
            float mn = fmaxf(m, d);
            s = s * __expf(m - mn) + __expf(d - mn);
            m = mn;
        }
        local = m + __logf(s);
    }
    for (int off = 32; off; off >>= 1) local += __shfl_down(local, off);
    __shared__ float part[4];
    const int wv = threadIdx.x >> 6, lane = threadIdx.x & 63;
    if (lane == 0) part[wv] = local;
    __syncthreads();
    if (threadIdx.x == 0) atomicAdd(out, part[0] + part[1] + part[2] + part[3]);
}

extern "C" void kernel_launch(void* const* d_in, const int* in_sizes, int n_in,
                              void* d_out, int out_size, void* d_ws, size_t ws_size,
                              hipStream_t stream) {
    const float* X  = (const float*)d_in[0];
    const float* M  = (const float*)d_in[1];
    const float* pi = (const float*)d_in[2];
    float* out = (float*)d_out;

    char* ws = (char*)d_ws;
    __bf16* Xb    = (__bf16*)ws;                          // 100352*256*2 = 51,380,224
    __bf16* Bt    = (__bf16*)(ws + 51380224);             // 1024*256*2   =    524,288
    float*  dens  = (float*)(ws + 51904512);              // 64*100352*4  = 25,690,112
    float*  cvec  = (float*)(ws + 77594624);              // 256 B

    const double half_p = 128.0;
    const float logSA = (float)(lgamma(half_p) - log(2.0) - half_p * log(M_PI));

    hipMemsetAsync(d_out, 0, sizeof(float), stream);
    prep_comp<<<64, 256, 0, stream>>>(M, pi, Bt, cvec, logSA);
    convert_X<<<12544, 256, 0, stream>>>(X, Xb);          // 100352*256/2048
    gemm_density<<<6272, 512, 0, stream>>>(Xb, Bt, cvec, dens);   // 784*8 tiles
    reduce_ll<<<391, 256, 0, stream>>>(dens, out);
}

// Round 6
// 169.341 us; speedup vs baseline: 1.2115x; 1.2115x over previous
//
#include <hip/hip_runtime.h>
#include <hip/hip_bf16.h>
#include <math.h>

#define NPTS 100000
#define NPAD 100352      // 784*128 row-padded; 98 row-tiles per XCD
#define KCOMP 64

typedef float v4f __attribute__((ext_vector_type(4)));
typedef __bf16 v8bf __attribute__((ext_vector_type(8)));
typedef __bf16 v4bf __attribute__((ext_vector_type(4)));

// Tiled operand layout: [tile][kt(8)][g(4)][r(128)][8 elems]
//   flat granule f = g*128 + r;  offset = (tile*8 + kt)*4096 + f*8  (elems)
// -> global_load_lds with per-lane f = base+lane is contiguous 1KB/instr, and
//    LDS holds granule-column-major: fragment read (hi*128 + row)*8 elems is a
//    contiguous 256B run per 16-lane group => 0 bank conflicts, no swizzle.

__device__ __forceinline__ void gload_lds16(const void* g, void* lds) {
    __builtin_amdgcn_global_load_lds(
        (const __attribute__((address_space(1))) void*)(uintptr_t)g,
        (__attribute__((address_space(3))) void*)(uint32_t)(uintptr_t)lds,
        16, 0, 0);
}

// ---------- kernel 1: per-component prep (Cholesky of I+M^T M, B = L^-1 M^T) ----------
__global__ __launch_bounds__(256) void prep_comp(const float* __restrict__ M,
                                                 const float* __restrict__ pi,
                                                 __bf16* __restrict__ Bt,
                                                 float* __restrict__ cvec,
                                                 float logSA) {
    __shared__ float Ml[256][16];
    __shared__ float S[16][17];
    __shared__ float sh_logpi;
    const int k = blockIdx.x, t = threadIdx.x;

    const float4* src = (const float4*)(M + (size_t)k * 4096 + (size_t)t * 16);
    float4 a0 = src[0], a1 = src[1], a2 = src[2], a3 = src[3];
    ((float4*)Ml[t])[0] = a0; ((float4*)Ml[t])[1] = a1;
    ((float4*)Ml[t])[2] = a2; ((float4*)Ml[t])[3] = a3;

    if (t < 64) {
        float v = pi[t];
        float mx = v;
        for (int off = 32; off; off >>= 1) mx = fmaxf(mx, __shfl_xor(mx, off));
        float e = __expf(v - mx);
        float s = e;
        for (int off = 32; off; off >>= 1) s += __shfl_xor(s, off);
        if (t == 0) sh_logpi = pi[k] - mx - logf(s);
    }
    __syncthreads();

    {
        int r = t >> 4, c = t & 15;
        float s = (r == c) ? 1.0f : 0.0f;
        for (int p = 0; p < 256; ++p) s += Ml[p][r] * Ml[p][c];
        S[r][c] = s;
    }
    __syncthreads();

    for (int j = 0; j < 16; ++j) {
        if (t == 0) S[j][j] = sqrtf(S[j][j]);
        __syncthreads();
        if (t > j && t < 16) S[t][j] = S[t][j] / S[j][j];
        __syncthreads();
        {
            int r = t >> 4, c = t & 15;
            if (r > j && c > j && c <= r) S[r][c] -= S[r][j] * S[c][j];
        }
        __syncthreads();
    }

    if (t == 0) {
        float ldet = 0.0f;
        for (int j = 0; j < 16; ++j) ldet += logf(S[j][j]);
        cvec[k] = logSA - ldet + sh_logpi;
    }

    float m[16] = {a0.x, a0.y, a0.z, a0.w, a1.x, a1.y, a1.z, a1.w,
                   a2.x, a2.y, a2.z, a2.w, a3.x, a3.y, a3.z, a3.w};
    float y[16];
#pragma unroll
    for (int r = 0; r < 16; ++r) {
        float v = m[r];
#pragma unroll
        for (int q = 0; q < r; ++q) v -= S[r][q] * y[q];
        y[r] = v / S[r][r];
    }
    // write tiled: crow = k*16+r (the GEMM "col"), p = t (K dim)
#pragma unroll
    for (int r = 0; r < 16; ++r) {
        const int crow = k * 16 + r;
        const size_t off = (size_t)((crow >> 7) * 32 + (t >> 3)) * 1024
                         + (size_t)(crow & 127) * 8 + (t & 7);
        Bt[off] = (__bf16)y[r];
    }
}

// ---------- kernel 2: X fp32 -> bf16, transposed into tiled layout ----------
// block = 64 rows x 256 cols of X; LDS-transpose (padded rows, conflict-free).
__global__ __launch_bounds__(256) void convert_X(const float* __restrict__ X,
                                                 __bf16* __restrict__ Xb) {
    __shared__ __bf16 T[64][264];   // +8 pad: row stride 132 dwords
    const int b = blockIdx.x;
    const int rt = b >> 1, half = b & 1;
    const int n0 = rt * 128 + half * 64;
    const int t = threadIdx.x;

    // phase 1: coalesced f32 reads -> bf16 -> LDS
#pragma unroll
    for (int j = 0; j < 16; ++j) {
        const int u = j * 256 + t;          // float4 index within 64x256 tile
        const int r = u >> 6, c4 = u & 63;
        const int n = n0 + r;
        float4 v = make_float4(0.f, 0.f, 0.f, 0.f);
        if (n < NPTS) v = ((const float4*)X)[(size_t)n * 64 + c4];
        v4bf o = {(__bf16)v.x, (__bf16)v.y, (__bf16)v.z, (__bf16)v.w};
        *(v4bf*)&T[r][c4 * 4] = o;
    }
    __syncthreads();

    // phase 2: granule-column-major coalesced writes
#pragma unroll
    for (int j = 0; j < 8; ++j) {
        const int fo = j * 256 + t;         // granule index within half-tile
        const int gk = fo >> 6, r = fo & 63;        // gk = kt*4+g (0..31)
        v8bf val = *(const v8bf*)&T[r][gk * 8];
        *(v8bf*)(Xb + (size_t)(rt * 32 + gk) * 1024 + (size_t)(half * 64 + r) * 8) = val;
    }
}

// ---------- kernel 3: persistent pipelined GEMM + fused density epilogue ----------
// 1280 blocks (5/CU), XCD-partitioned jobs; BK=32 double-buffer (32 KB LDS);
// flat slot stream: STAGE(s+1) || compute(s); one vmcnt(0)+barrier per slot.
__global__ __launch_bounds__(256, 4) void gemm_density(const __bf16* __restrict__ Xb,
                                                       const __bf16* __restrict__ Bt,
                                                       const float* __restrict__ cvec,
                                                       float* __restrict__ dens) {
    __shared__ __bf16 As[2][4096];   // 512 granules x 8 elems = 8 KB per buf
    __shared__ __bf16 Bs[2][4096];
    const int bid = blockIdx.x;
    const int x = bid & 7;           // XCD (heuristic round-robin)
    const int i = bid >> 3;          // 0..159 within XCD
    const int xbase = x * 98;        // row-tile range of this XCD
    const int tid = threadIdx.x;
    const int w = tid >> 6, lane = tid & 63;
    const int wm = w >> 1, wn = w & 1;
    const int lo = lane & 15, hi = lane >> 4;

    const int njobs = (i < 144) ? 5 : 4;     // 784 jobs/XCD over 160 blocks
    const int nslots = njobs << 3;

#define SLOT_RC(s, rt_, ct_, kt_) do {                     \
    const int jx_ = (s) >> 3; kt_ = (s) & 7;               \
    const int Jl_ = i + jx_ * 160;                         \
    rt_ = xbase + (Jl_ >> 3); ct_ = Jl_ & 7;               \
} while (0)

#define STAGE(buf, rt_, ct_, kt_) do {                                           \
    _Pragma("unroll")                                                            \
    for (int q = 0; q < 2; ++q) {                                                \
        const int fb = (q << 8) + (w << 6);   /* wave-uniform granule base */    \
        const int f = fb + lane;                                                 \
        gload_lds16(Xb + ((size_t)((rt_) * 8 + (kt_)) * 512 + f) * 8,            \
                    As[buf] + ((size_t)fb << 3));                                \
        gload_lds16(Bt + ((size_t)((ct_) * 8 + (kt_)) * 512 + f) * 8,            \
                    Bs[buf] + ((size_t)fb << 3));                                \
    }                                                                            \
} while (0)

    {
        int rt, ct, kt;
        SLOT_RC(0, rt, ct, kt);
        STAGE(0, rt, ct, kt);
    }
    asm volatile("s_waitcnt vmcnt(0)" ::: "memory");
    __syncthreads();

    v4f acc[4][4] = {};
    for (int s = 0; s < nslots; ++s) {
        const int buf = s & 1;
        if (s + 1 < nslots) {
            int rt2, ct2, kt2;
            SLOT_RC(s + 1, rt2, ct2, kt2);
            STAGE(buf ^ 1, rt2, ct2, kt2);
        }

        // fragment reads: contiguous 256B per 16-lane group -> conflict-free
        v8bf af[4], bg[4];
#pragma unroll
        for (int m = 0; m < 4; ++m)
            af[m] = *(const v8bf*)&As[buf][((hi << 7) + wm * 64 + m * 16 + lo) << 3];
#pragma unroll
        for (int n = 0; n < 4; ++n)
            bg[n] = *(const v8bf*)&Bs[buf][((hi << 7) + wn * 64 + n * 16 + lo) << 3];
#pragma unroll
        for (int m = 0; m < 4; ++m)
#pragma unroll
            for (int n = 0; n < 4; ++n)
                acc[m][n] = __builtin_amdgcn_mfma_f32_16x16x32_bf16(af[m], bg[n], acc[m][n], 0, 0, 0);

        if ((s & 7) == 7) {
            // job done: fused quad -> density epilogue, then reset acc
            int rt, ct, kt;
            SLOT_RC(s, rt, ct, kt);
            const int row0 = rt << 7, col0 = ct << 7;
#pragma unroll
            for (int m = 0; m < 4; ++m) {
                const int rowb = row0 + wm * 64 + m * 16 + hi * 4;
#pragma unroll
                for (int n = 0; n < 4; ++n) {
                    const int kc = (col0 >> 4) + (wn << 2) + n;
                    v4f q = acc[m][n] * acc[m][n];
#pragma unroll
                    for (int off = 1; off < 16; off <<= 1) {
                        v4f tq;
                        tq[0] = __shfl_xor(q[0], off);
                        tq[1] = __shfl_xor(q[1], off);
                        tq[2] = __shfl_xor(q[2], off);
                        tq[3] = __shfl_xor(q[3], off);
                        q += tq;
                    }
                    if (lo < 4) {
                        const float d = cvec[kc] - 128.0f * __logf(1.0f - q[lo]);
                        dens[(size_t)kc * NPAD + rowb + lo] = d;
                    }
                    acc[m][n] = (v4f)(0.0f);
                }
            }
        }

        asm volatile("s_waitcnt vmcnt(0)" ::: "memory");
        __syncthreads();
    }
#undef STAGE
#undef SLOT_RC
}

// ---------- kernel 4: logsumexp over k, global sum ----------
__global__ __launch_bounds__(256) void reduce_ll(const float* __restrict__ dens,
                                                 float* __restrict__ out) {
    const int n = blockIdx.x * 256 + threadIdx.x;
    float local = 0.0f;
    if (n < NPTS) {
        float m = dens[n];
        float s = 1.0f;
        for (int k = 1; k < 64; ++k) {
            float d = dens[(size_t)k * NPAD + n];
            float mn = fmaxf(m, d);
            s = s * __expf(m - mn) + __expf(d - mn);
            m = mn;
        }
        local = m + __logf(s);
    }
    for (int off = 32; off; off >>= 1) local += __shfl_down(local, off);
    __shared__ float part[4];
    const int wv = threadIdx.x >> 6, lane = threadIdx.x & 63;
    if (lane == 0) part[wv] = local;
    __syncthreads();
    if (threadIdx.x == 0) atomicAdd(out, part[0] + part[1] + part[2] + part[3]);
}

extern "C" void kernel_launch(void* const* d_in, const int* in_sizes, int n_in,
                              void* d_out, int out_size, void* d_ws, size_t ws_size,
                              hipStream_t stream) {
    const float* X  = (const float*)d_in[0];
    const float* M  = (const float*)d_in[1];
    const float* pi = (const float*)d_in[2];
    float* out = (float*)d_out;

    char* ws = (char*)d_ws;
    __bf16* Xb    = (__bf16*)ws;                          // 100352*256*2 = 51,380,224
    __bf16* Bt    = (__bf16*)(ws + 51380224);             // 1024*256*2   =    524,288
    float*  dens  = (float*)(ws + 51904512);              // 64*100352*4  = 25,690,112
    float*  cvec  = (float*)(ws + 77594624);              // 256 B

    const double half_p = 128.0;
    const float logSA = (float)(lgamma(half_p) - log(2.0) - half_p * log(M_PI));

    hipMemsetAsync(d_out, 0, sizeof(float), stream);
    prep_comp<<<64, 256, 0, stream>>>(M, pi, Bt, cvec, logSA);
    convert_X<<<1568, 256, 0, stream>>>(X, Xb);           // 784 tiles x 2 halves
    gemm_density<<<1280, 256, 0, stream>>>(Xb, Bt, cvec, dens);   // persistent, 5/CU
    reduce_ll<<<391, 256, 0, stream>>>(dens, out);
}